// Round 1
// baseline (363.283 us; speedup 1.0000x reference)
//
#include <hip/hip_runtime.h>

typedef __attribute__((ext_vector_type(8))) short short8;
typedef __attribute__((ext_vector_type(4))) float f32x4;
typedef __attribute__((ext_vector_type(8))) unsigned short u16x8;
typedef __attribute__((ext_vector_type(4))) unsigned short u16x4;
typedef unsigned short u16;

#define DEVINL __device__ __forceinline__

DEVINL u16 f2bf(float f) {
  unsigned u = __builtin_bit_cast(unsigned, f);
  unsigned r = (u + 0x7fffu + ((u >> 16) & 1u)) >> 16;  // RNE
  return (u16)r;
}
DEVINL float bf2f(u16 h) {
  unsigned u = ((unsigned)h) << 16;
  return __builtin_bit_cast(float, u);
}
// LDS tiles: [64 rows][64 bf16 cols] = 128 B rows = 8 chunks of 16 B.
// XOR swizzle keeps 16-lane column reads conflict-free; writer & reader share it.
DEVINL int swzc(int row, int chunk) { return chunk ^ ((row ^ (row >> 3)) & 7); }
DEVINL int tile_byte(int row, int chunk) { return row * 128 + swzc(row, chunk) * 16; }

// ---------------- W conversion ----------------
__global__ void kw_convert(const float* __restrict__ P1, const float* __restrict__ q,
                           const float* __restrict__ k, const float* __restrict__ P4,
                           u16* __restrict__ Wbf) {
  int t = threadIdx.x;
  const float* srcs[4] = {P1, q, k, P4};
  for (int w = 0; w < 4; ++w)
    for (int e = t; e < 4096; e += 256) Wbf[w * 4096 + e] = f2bf(srcs[w][e]);
}

// ---------------- means ----------------
__global__ void k_mean3(const float* __restrict__ A, float* __restrict__ mean3, int g0) {
  int idx = blockIdx.x * 256 + threadIdx.x;  // (bg, i, x, y)
  int y = idx & 31, x = (idx >> 5) & 63, i = (idx >> 11) & 63, bg = idx >> 17;
  const float* p = A + ((((long)(g0 + bg) * 64 + i) * 64 + x) * 32 + y) * 16;
  float s = 0.0f;
#pragma unroll
  for (int z = 0; z < 16; z += 4) {
    f32x4 v = *(const f32x4*)(p + z);
    s += v[0] + v[1] + v[2] + v[3];
  }
  mean3[idx] = s * (1.0f / 16.0f);
}

__global__ void k_mean2(const float* __restrict__ A, float* __restrict__ mean2, int g0) {
  int idx = blockIdx.x * 256 + threadIdx.x;  // (bg, i, x, z)
  int z = idx & 15, x = (idx >> 4) & 63, i = (idx >> 10) & 63, bg = idx >> 16;
  const float* p = A + (((long)(g0 + bg) * 64 + i) * 64 + x) * 512 + z;
  float s = 0.0f;
#pragma unroll
  for (int y = 0; y < 32; ++y) s += p[y * 16];
  mean2[idx] = s * (1.0f / 32.0f);
}

// ---------------- small projections of means ----------------
__global__ void k_a2(const float* __restrict__ P2, const float* __restrict__ mean3,
                     float* __restrict__ A2) {
  int lid = blockIdx.x * 256 + threadIdx.x;  // (x,y)
  int y = lid & 31, x = lid >> 5;
  int c = blockIdx.y, bg = blockIdx.z;
  const float* m3 = mean3 + (long)bg * 131072 + x * 32 + y;
  float s = 0.0f;
#pragma unroll 8
  for (int i = 0; i < 64; ++i) s += P2[c * 64 + i] * m3[i * 2048];
  A2[(((long)bg * 64 + c) * 64 + x) * 32 + y] = s;
}

__global__ void k_a3(const float* __restrict__ P3, const float* __restrict__ mean2,
                     float* __restrict__ A3) {
  int lid = blockIdx.x * 256 + threadIdx.x;  // (x,z)
  int z = lid & 15, x = lid >> 4;
  int c = blockIdx.y, bg = blockIdx.z;
  const float* m2 = mean2 + (long)bg * 65536 + x * 16 + z;
  float s = 0.0f;
#pragma unroll 8
  for (int i = 0; i < 64; ++i) s += P3[c * 64 + i] * m2[i * 1024];
  A3[(((long)bg * 64 + c) * 64 + x) * 16 + z] = s;
}

// ---------------- projections: A1,Q,K,V = {P1,q,k,P4} @ A ----------------
__global__ __launch_bounds__(256) void k_proj(const float* __restrict__ A,
                                              const u16* __restrict__ Wbf,
                                              u16* __restrict__ A1, u16* __restrict__ Q,
                                              u16* __restrict__ Km, u16* __restrict__ V,
                                              int g0) {
  __shared__ __align__(16) u16 tile[64 * 64];  // [s][i] bf16, swizzled
  const int t = threadIdx.x;
  const int w = t >> 6, l = t & 63;
  const int lr = l & 15, lh = l >> 4;
  const int bg = blockIdx.y;
  const long bglob = g0 + bg;
  const int sb0 = blockIdx.x * 64;

  // W fragments (B-operand: B[k=i][n=o] = W[o][i]); wave w owns matrix w
  short8 wf[4][2];
  const u16* wb = Wbf + w * 4096;
#pragma unroll
  for (int ot = 0; ot < 4; ++ot)
#pragma unroll
    for (int ks = 0; ks < 2; ++ks)
      wf[ot][ks] = *(const short8*)(wb + (ot * 16 + lr) * 64 + ks * 32 + lh * 8);

  // stage A-tile transposed to [s][i] bf16
  {
    const int i4 = t & 15, s4 = t >> 4;
    const float* ap = A + (bglob * 64 + i4 * 4) * 32768 + sb0 + s4 * 4;
    f32x4 v0 = *(const f32x4*)(ap);
    f32x4 v1 = *(const f32x4*)(ap + 32768);
    f32x4 v2 = *(const f32x4*)(ap + 65536);
    f32x4 v3 = *(const f32x4*)(ap + 98304);
#pragma unroll
    for (int c = 0; c < 4; ++c) {
      int srow = s4 * 4 + c;
      u16x4 pk = {f2bf(v0[c]), f2bf(v1[c]), f2bf(v2[c]), f2bf(v3[c])};
      *(u16x4*)((char*)tile + tile_byte(srow, i4 >> 1) + (i4 & 1) * 8) = pk;
    }
  }
  __syncthreads();

  f32x4 acc[4][4];
#pragma unroll
  for (int st = 0; st < 4; ++st)
#pragma unroll
    for (int ot = 0; ot < 4; ++ot) acc[st][ot] = {0.0f, 0.0f, 0.0f, 0.0f};

#pragma unroll
  for (int ks = 0; ks < 2; ++ks) {
    short8 af[4];
#pragma unroll
    for (int st = 0; st < 4; ++st) {
      int row = st * 16 + lr;
      af[st] = *(const short8*)((const char*)tile + tile_byte(row, ks * 4 + lh));
    }
#pragma unroll
    for (int st = 0; st < 4; ++st)
#pragma unroll
      for (int ot = 0; ot < 4; ++ot)
        acc[st][ot] =
            __builtin_amdgcn_mfma_f32_16x16x32_bf16(af[st], wf[ot][ks], acc[st][ot], 0, 0, 0);
  }

  // D[s][o]: lane holds col o = lr, rows s = 4*lh + r  -> s-contiguous ushort4 stores
  u16* outp = (w == 0) ? A1 : (w == 1) ? Q : (w == 2) ? Km : V;
  outp += (long)bg * 64 * 32768;
#pragma unroll
  for (int st = 0; st < 4; ++st)
#pragma unroll
    for (int ot = 0; ot < 4; ++ot) {
      int co = ot * 16 + lr;
      int s = sb0 + st * 16 + lh * 4;
      u16x4 pk = {f2bf(acc[st][ot][0]), f2bf(acc[st][ot][1]), f2bf(acc[st][ot][2]),
                  f2bf(acc[st][ot][3])};
      *(u16x4*)(outp + (long)co * 32768 + s) = pk;
    }
}

// ---------------- attention + combine + relu + BN partials ----------------
__global__ __launch_bounds__(256) void k_attn(const u16* __restrict__ Qg,
                                              const u16* __restrict__ Kg,
                                              const u16* __restrict__ Vg,
                                              const u16* __restrict__ A1g,
                                              const float* __restrict__ A2g,
                                              const float* __restrict__ A3g,
                                              float* __restrict__ out,
                                              float* __restrict__ partials, int g0) {
  __shared__ __align__(16) u16 Qc[4096], Kc[4096], Vt[4096], An[4096];
  __shared__ float red[8];
  const int t = threadIdx.x, w = t >> 6, l = t & 63;
  const int lr = l & 15, lh = l >> 4;
  const int c = blockIdx.x, bg = blockIdx.y;
  const long bglob = g0 + bg;
  const long base = ((long)bg * 64 + c) * 32768;
  const u16* Qp = Qg + base;
  const u16* Kp = Kg + base;
  const u16* Vp = Vg + base;
  const u16* A1p = A1g + base;

  // ---- phase 1: Alpha = Q K^T (contraction over m=512, 8 chunks of 64) ----
  f32x4 accA[4];
#pragma unroll
  for (int yt = 0; yt < 4; ++yt) accA[yt] = {0.0f, 0.0f, 0.0f, 0.0f};

  const int srow = t >> 3, scc = t & 7;
  for (int mc = 0; mc < 8; ++mc) {
#pragma unroll
    for (int it = 0; it < 2; ++it) {
      int row = srow + it * 32;
      int gch = scc ^ ((row ^ (row >> 3)) & 7);  // pre-swizzled global chunk
      u16x8 qv = *(const u16x8*)(Qp + row * 512 + mc * 64 + gch * 8);
      u16x8 kv = *(const u16x8*)(Kp + row * 512 + mc * 64 + gch * 8);
      *(u16x8*)((char*)Qc + row * 128 + scc * 16) = qv;
      *(u16x8*)((char*)Kc + row * 128 + scc * 16) = kv;
    }
    __syncthreads();
    short8 qf[2];
#pragma unroll
    for (int ks = 0; ks < 2; ++ks)
      qf[ks] = *(const short8*)((const char*)Qc + tile_byte(16 * w + lr, ks * 4 + lh));
#pragma unroll
    for (int ks = 0; ks < 2; ++ks)
#pragma unroll
      for (int yt = 0; yt < 4; ++yt) {
        short8 kf = *(const short8*)((const char*)Kc + tile_byte(yt * 16 + lr, ks * 4 + lh));
        accA[yt] = __builtin_amdgcn_mfma_f32_16x16x32_bf16(qf[ks], kf, accA[yt], 0, 0, 0);
      }
    __syncthreads();
  }

  // ---- phase 2: row L2-norm + Alpha_norm -> LDS (wave-local rows) ----
  // lane holds Alpha[x = 16w + 4*lh + r][y = yt*16 + lr]
  float rsq[4];
#pragma unroll
  for (int r = 0; r < 4; ++r) {
    float s = 0.0f;
#pragma unroll
    for (int yt = 0; yt < 4; ++yt) s += accA[yt][r] * accA[yt][r];
#pragma unroll
    for (int msk = 1; msk < 16; msk <<= 1) s += __shfl_xor(s, msk);
    rsq[r] = rsqrtf(s);
  }
#pragma unroll
  for (int yt = 0; yt < 4; ++yt)
#pragma unroll
    for (int r = 0; r < 4; ++r) {
      int xr = 16 * w + 4 * lh + r;
      int y = yt * 16 + lr;
      *(u16*)((char*)An + xr * 128 + swzc(xr, y >> 3) * 16 + (y & 7) * 2) =
          f2bf(fabsf(accA[yt][r]) * rsq[r]);
    }

  // ---- phase 3: Y^T = V_t * An^T, fused combine+relu+store+BN partials ----
  float ls = 0.0f, lsq = 0.0f;
  const float* A2p = A2g + ((long)bg * 64 + c) * 2048;  // [x][y]
  const float* A3p = A3g + ((long)bg * 64 + c) * 1024;  // [x][z]
  float* outp = out + (bglob * 64 + c) * 32768;
  const int m4 = t & 15, y4 = t >> 4;
  const int x = 16 * w + lr;

  for (int mc = 0; mc < 8; ++mc) {
    __syncthreads();
    u16x4 vr[4];
#pragma unroll
    for (int r = 0; r < 4; ++r)
      vr[r] = *(const u16x4*)(Vp + (y4 * 4 + r) * 512 + mc * 64 + m4 * 4);
#pragma unroll
    for (int ci = 0; ci < 4; ++ci) {
      int mrow = m4 * 4 + ci;
      u16x4 pk = {vr[0][ci], vr[1][ci], vr[2][ci], vr[3][ci]};
      *(u16x4*)((char*)Vt + tile_byte(mrow, y4 >> 1) + (y4 & 1) * 8) = pk;
    }
    __syncthreads();

    f32x4 accY[4];
#pragma unroll
    for (int mt = 0; mt < 4; ++mt) accY[mt] = {0.0f, 0.0f, 0.0f, 0.0f};
#pragma unroll
    for (int ks = 0; ks < 2; ++ks) {
      short8 anf = *(const short8*)((const char*)An + tile_byte(16 * w + lr, ks * 4 + lh));
#pragma unroll
      for (int mt = 0; mt < 4; ++mt) {
        short8 vf = *(const short8*)((const char*)Vt + tile_byte(mt * 16 + lr, ks * 4 + lh));
        accY[mt] = __builtin_amdgcn_mfma_f32_16x16x32_bf16(vf, anf, accY[mt], 0, 0, 0);
      }
    }
    // epilogue: D[m][x]: lane col x = 16w+lr, rows m = mt*16 + 4*lh + r
    f32x4 a3v = *(const f32x4*)(A3p + x * 16 + lh * 4);
#pragma unroll
    for (int mt = 0; mt < 4; ++mt) {
      float a2v = A2p[x * 32 + mc * 4 + mt];
      int mbase = mc * 64 + mt * 16 + lh * 4;
      u16x4 a1v = *(const u16x4*)(A1p + x * 512 + mbase);
      f32x4 o;
#pragma unroll
      for (int r = 0; r < 4; ++r) {
        float val = bf2f(a1v[r]) + 0.1f * (a2v + a3v[r] + accY[mt][r]);
        val = fmaxf(val, 0.0f);
        o[r] = val;
        ls += val;
        lsq += val * val;
      }
      *(f32x4*)(outp + x * 512 + mbase) = o;
    }
  }

  // ---- phase 4: deterministic block reduction of BN partials ----
#pragma unroll
  for (int off = 32; off > 0; off >>= 1) {
    ls += __shfl_xor(ls, off);
    lsq += __shfl_xor(lsq, off);
  }
  if (l == 0) {
    red[w] = ls;
    red[4 + w] = lsq;
  }
  __syncthreads();
  if (t == 0) {
    partials[2 * (bglob * 64 + c) + 0] = red[0] + red[1] + red[2] + red[3];
    partials[2 * (bglob * 64 + c) + 1] = red[4] + red[5] + red[6] + red[7];
  }
}

// ---------------- BN stats finalize ----------------
__global__ void k_stats(const float* __restrict__ partials, const float* __restrict__ gamma,
                        const float* __restrict__ beta, float* __restrict__ sb) {
  int c = threadIdx.x;
  if (c >= 64) return;
  float S = 0.0f, SQ = 0.0f;
  for (int b = 0; b < 16; ++b) {
    S += partials[2 * (b * 64 + c) + 0];
    SQ += partials[2 * (b * 64 + c) + 1];
  }
  const float N = 524288.0f;
  float mean = S / N;
  float var = SQ / N - mean * mean;
  float rs = rsqrtf(var + 1e-5f);
  float scale = gamma[c] * rs;
  sb[c] = scale;
  sb[64 + c] = beta[c] - mean * scale;
}

// ---------------- BN affine ----------------
__global__ void k_bn(float* __restrict__ out, const float* __restrict__ sb) {
  long idx = ((long)blockIdx.x * 256 + threadIdx.x) * 4;
  int c = (int)((idx >> 15) & 63);
  float scale = sb[c], bias = sb[64 + c];
  f32x4 v = *(f32x4*)(out + idx);
#pragma unroll
  for (int r = 0; r < 4; ++r) v[r] = v[r] * scale + bias;
  *(f32x4*)(out + idx) = v;
}

extern "C" void kernel_launch(void* const* d_in, const int* in_sizes, int n_in, void* d_out,
                              int out_size, void* d_ws, size_t ws_size, hipStream_t stream) {
  (void)in_sizes; (void)n_in; (void)out_size;
  const float* A = (const float*)d_in[0];
  const float* P1 = (const float*)d_in[1];
  const float* P2 = (const float*)d_in[2];
  const float* P3 = (const float*)d_in[3];
  const float* P4 = (const float*)d_in[4];
  const float* q = (const float*)d_in[5];
  const float* k = (const float*)d_in[6];
  const float* gamma = (const float*)d_in[7];
  const float* beta = (const float*)d_in[8];
  float* out = (float*)d_out;
  char* ws = (char*)d_ws;

  u16* Wbf = (u16*)ws;                     // 32 KiB
  float* partials = (float*)(ws + 32768);  // 8 KiB (16*64*2)
  float* sb = (float*)(ws + 40960);        // 512 B
  const size_t GR = 49152;
  const size_t SZ_M = (size_t)64 * 32768 * 2;      // 4 MiB / batch / matrix (bf16)
  const size_t SZ_MEAN3 = (size_t)64 * 64 * 32 * 4;  // 512 KiB
  const size_t SZ_MEAN2 = (size_t)64 * 64 * 16 * 4;  // 256 KiB
  const size_t perb = 4 * SZ_M + 2 * SZ_MEAN3 + 2 * SZ_MEAN2;  // ~17.5 MiB
  int G = 1;
  if (ws_size > GR + perb) G = (int)((ws_size - GR) / perb);
  if (G > 16) G = 16;
  if (G < 1) G = 1;

  u16* A1 = (u16*)(ws + GR);
  u16* Qw = (u16*)(ws + GR + (size_t)G * SZ_M);
  u16* Kw = (u16*)(ws + GR + (size_t)G * SZ_M * 2);
  u16* Vw = (u16*)(ws + GR + (size_t)G * SZ_M * 3);
  float* mean3 = (float*)(ws + GR + (size_t)G * SZ_M * 4);
  float* mean2 = (float*)((char*)mean3 + (size_t)G * SZ_MEAN3);
  float* A2 = (float*)((char*)mean2 + (size_t)G * SZ_MEAN2);
  float* A3 = (float*)((char*)A2 + (size_t)G * SZ_MEAN3);

  kw_convert<<<1, 256, 0, stream>>>(P1, q, k, P4, Wbf);
  for (int g0 = 0; g0 < 16; g0 += G) {
    int Gc = (16 - g0) < G ? (16 - g0) : G;
    k_mean3<<<Gc * 512, 256, 0, stream>>>(A, mean3, g0);
    k_mean2<<<Gc * 256, 256, 0, stream>>>(A, mean2, g0);
    k_a2<<<dim3(8, 64, Gc), 256, 0, stream>>>(P2, mean3, A2);
    k_a3<<<dim3(4, 64, Gc), 256, 0, stream>>>(P3, mean2, A3);
    k_proj<<<dim3(512, Gc), 256, 0, stream>>>(A, Wbf, A1, Qw, Kw, Vw, g0);
    k_attn<<<dim3(64, Gc), 256, 0, stream>>>(Qw, Kw, Vw, A1, A2, A3, out, partials, g0);
  }
  k_stats<<<1, 64, 0, stream>>>(partials, gamma, beta, sb);
  k_bn<<<32768, 256, 0, stream>>>(out, sb);
}

// Round 2
// 302.613 us; speedup vs baseline: 1.2005x; 1.2005x over previous
//
#include <hip/hip_runtime.h>

typedef __attribute__((ext_vector_type(8))) short short8;
typedef __attribute__((ext_vector_type(4))) float f32x4;
typedef __attribute__((ext_vector_type(8))) unsigned short u16x8;
typedef __attribute__((ext_vector_type(4))) unsigned short u16x4;
typedef unsigned short u16;

#define DEVINL __device__ __forceinline__

DEVINL u16 f2bf(float f) {
  unsigned u = __builtin_bit_cast(unsigned, f);
  unsigned r = (u + 0x7fffu + ((u >> 16) & 1u)) >> 16;  // RNE
  return (u16)r;
}
DEVINL float bf2f(u16 h) {
  unsigned u = ((unsigned)h) << 16;
  return __builtin_bit_cast(float, u);
}
// LDS tiles: [rows][64 bf16 cols] = 128 B rows = 8 chunks of 16 B.
// XOR swizzle keeps column reads conflict-free; writer & reader share it.
DEVINL int swzc(int row, int chunk) { return chunk ^ ((row ^ (row >> 3)) & 7); }
DEVINL int tile_byte(int row, int chunk) { return row * 128 + swzc(row, chunk) * 16; }

// ---------------- W conversion: P1,q,k,P4,P2,P3 -> bf16 ----------------
__global__ void kw_convert(const float* __restrict__ P1, const float* __restrict__ q,
                           const float* __restrict__ k, const float* __restrict__ P4,
                           const float* __restrict__ P2, const float* __restrict__ P3,
                           u16* __restrict__ Wbf) {
  int t = threadIdx.x;
  const float* srcs[6] = {P1, q, k, P4, P2, P3};
  for (int w = 0; w < 6; ++w)
    for (int e = t; e < 4096; e += 256) Wbf[w * 4096 + e] = f2bf(srcs[w][e]);
}

// ---------------- fused: means + A2/A3 + projections ----------------
// block = (x, bg): reads A[i=0..63][s = x*512 .. +511] once.
__global__ __launch_bounds__(512, 4) void k_projA(
    const float* __restrict__ A, const u16* __restrict__ Wbf, u16* __restrict__ A1,
    u16* __restrict__ Q, u16* __restrict__ Km, u16* __restrict__ V,
    float* __restrict__ A2g, float* __restrict__ A3g, int g0) {
  __shared__ __align__(16) u16 tile[512 * 64];  // [s][i] bf16, swizzled, 64 KiB
  __shared__ __align__(16) u16 meanT[48 * 64];  // rows 0-31: mean3[y][i]; 32-47: mean2[z][i]
  const int t = threadIdx.x;
  const int w = t >> 6, l = t & 63;
  const int lr = l & 15, lh = l >> 4;
  const int x = blockIdx.x, bg = blockIdx.y;
  const long bglob = g0 + bg;

  // ---- stage A -> tile (transpose [i][s] -> [s][i], f32 -> bf16) ----
  {
    const int s4 = t & 31, i4 = t >> 5;  // i = i4*4 + c, s = si*128 + s4*4 + e
    const float* ap = A + (bglob * 64 + i4 * 4) * 32768 + (long)x * 512 + s4 * 4;
#pragma unroll
    for (int si = 0; si < 4; ++si) {
      f32x4 v0 = *(const f32x4*)(ap + si * 128);
      f32x4 v1 = *(const f32x4*)(ap + si * 128 + 32768);
      f32x4 v2 = *(const f32x4*)(ap + si * 128 + 65536);
      f32x4 v3 = *(const f32x4*)(ap + si * 128 + 98304);
#pragma unroll
      for (int e = 0; e < 4; ++e) {
        int s = si * 128 + s4 * 4 + e;
        u16x4 pk = {f2bf(v0[e]), f2bf(v1[e]), f2bf(v2[e]), f2bf(v3[e])};
        *(u16x4*)((char*)tile + tile_byte(s, i4 >> 1) + (i4 & 1) * 8) = pk;
      }
    }
  }
  __syncthreads();

  // ---- mean3[y][i] = (1/16) sum_z tile[y*16+z][i]  (t -> ic, zh, y) ----
  {
    const int ic = t & 7, zh = (t >> 3) & 1, y = t >> 4;  // y in 0..31
    float acc[8] = {0, 0, 0, 0, 0, 0, 0, 0};
#pragma unroll
    for (int zz = 0; zz < 8; ++zz) {
      int row = y * 16 + zh * 8 + zz;
      u16x8 v = *(const u16x8*)((const char*)tile + tile_byte(row, ic));
#pragma unroll
      for (int e = 0; e < 8; ++e) acc[e] += bf2f(v[e]);
    }
#pragma unroll
    for (int e = 0; e < 8; ++e) acc[e] += __shfl_xor(acc[e], 8);
    if (zh == 0) {
      u16x8 pk;
#pragma unroll
      for (int e = 0; e < 8; ++e) pk[e] = f2bf(acc[e] * (1.0f / 16.0f));
      *(u16x8*)((char*)meanT + tile_byte(y, ic)) = pk;
    }
  }
  // ---- mean2[z][i] = (1/32) sum_y tile[y*16+z][i]  (t -> ic, yg, z) ----
  {
    const int ic = t & 7, yg = (t >> 3) & 3, z = t >> 5;  // z in 0..15
    float acc[8] = {0, 0, 0, 0, 0, 0, 0, 0};
#pragma unroll
    for (int yy = 0; yy < 8; ++yy) {
      int row = (yg * 8 + yy) * 16 + z;
      u16x8 v = *(const u16x8*)((const char*)tile + tile_byte(row, ic));
#pragma unroll
      for (int e = 0; e < 8; ++e) acc[e] += bf2f(v[e]);
    }
#pragma unroll
    for (int e = 0; e < 8; ++e) {
      acc[e] += __shfl_xor(acc[e], 8);
      acc[e] += __shfl_xor(acc[e], 16);
    }
    if (yg == 0) {
      u16x8 pk;
#pragma unroll
      for (int e = 0; e < 8; ++e) pk[e] = f2bf(acc[e] * (1.0f / 32.0f));
      *(u16x8*)((char*)meanT + tile_byte(32 + z, ic)) = pk;
    }
  }
  __syncthreads();

  // ---- A2/A3 via MFMA on waves 0-2: D[o][col] = W{P2,P3} . meanT ----
  if (w < 3) {
    const int ct = w;  // 0,1: A2 col-tiles (y); 2: A3 (z), meanT rows 32..47
    const u16* wb2 = Wbf + (w == 2 ? 5 : 4) * 4096;
    const int colrow = (w == 2) ? 32 + lr : ct * 16 + lr;
    f32x4 acc2[4];
#pragma unroll
    for (int ot = 0; ot < 4; ++ot) acc2[ot] = {0.0f, 0.0f, 0.0f, 0.0f};
#pragma unroll
    for (int ks = 0; ks < 2; ++ks) {
      short8 mf = *(const short8*)((const char*)meanT + tile_byte(colrow, ks * 4 + lh));
#pragma unroll
      for (int ot = 0; ot < 4; ++ot) {
        short8 w2f = *(const short8*)(wb2 + (ot * 16 + lr) * 64 + ks * 32 + lh * 8);
        acc2[ot] = __builtin_amdgcn_mfma_f32_16x16x32_bf16(w2f, mf, acc2[ot], 0, 0, 0);
      }
    }
    // D[o][col]: lane col = lr, rows o = ot*16 + lh*4 + r
#pragma unroll
    for (int ot = 0; ot < 4; ++ot)
#pragma unroll
      for (int r = 0; r < 4; ++r) {
        int o = ot * 16 + lh * 4 + r;
        if (w < 2)
          A2g[(((long)bg * 64 + o) * 64 + x) * 32 + ct * 16 + lr] = acc2[ot][r];
        else
          A3g[(((long)bg * 64 + o) * 64 + x) * 16 + lr] = acc2[ot][r];
      }
  }

  // ---- main: A1,Q,K,V = {P1,q,k,P4} @ A (wave = matrix x s-half) ----
  const int m = w & 3, sh = w >> 2;
  const u16* wb = Wbf + m * 4096;
  short8 wf[4][2];
#pragma unroll
  for (int ot = 0; ot < 4; ++ot)
#pragma unroll
    for (int ks = 0; ks < 2; ++ks)
      wf[ot][ks] = *(const short8*)(wb + (ot * 16 + lr) * 64 + ks * 32 + lh * 8);
  u16* outp = (m == 0) ? A1 : (m == 1) ? Q : (m == 2) ? Km : V;
  outp += (long)bg * 64 * 32768;

  for (int st = 0; st < 16; ++st) {
    const int srow = sh * 256 + st * 16 + lr;
    short8 af0 = *(const short8*)((const char*)tile + tile_byte(srow, lh));
    short8 af1 = *(const short8*)((const char*)tile + tile_byte(srow, 4 + lh));
    f32x4 acc[4];
#pragma unroll
    for (int ot = 0; ot < 4; ++ot) acc[ot] = {0.0f, 0.0f, 0.0f, 0.0f};
#pragma unroll
    for (int ot = 0; ot < 4; ++ot) {
      acc[ot] = __builtin_amdgcn_mfma_f32_16x16x32_bf16(af0, wf[ot][0], acc[ot], 0, 0, 0);
      acc[ot] = __builtin_amdgcn_mfma_f32_16x16x32_bf16(af1, wf[ot][1], acc[ot], 0, 0, 0);
    }
    // D[s][o]: lane col o = ot*16 + lr, rows s = base + lh*4 + r
    const int sbase = x * 512 + sh * 256 + st * 16 + lh * 4;
#pragma unroll
    for (int ot = 0; ot < 4; ++ot) {
      u16x4 pk = {f2bf(acc[ot][0]), f2bf(acc[ot][1]), f2bf(acc[ot][2]), f2bf(acc[ot][3])};
      *(u16x4*)(outp + (long)(ot * 16 + lr) * 32768 + sbase) = pk;
    }
  }
}

// ---------------- attention + combine + relu + BN partials ----------------
__global__ __launch_bounds__(256) void k_attn(const u16* __restrict__ Qg,
                                              const u16* __restrict__ Kg,
                                              const u16* __restrict__ Vg,
                                              const u16* __restrict__ A1g,
                                              const float* __restrict__ A2g,
                                              const float* __restrict__ A3g,
                                              float* __restrict__ out,
                                              float* __restrict__ partials, int g0) {
  __shared__ __align__(16) u16 Qc[4096], Kc[4096], Vt[4096], An[4096];
  __shared__ float red[8];
  const int t = threadIdx.x, w = t >> 6, l = t & 63;
  const int lr = l & 15, lh = l >> 4;
  const int c = blockIdx.x, bg = blockIdx.y;
  const long bglob = g0 + bg;
  const long base = ((long)bg * 64 + c) * 32768;
  const u16* Qp = Qg + base;
  const u16* Kp = Kg + base;
  const u16* Vp = Vg + base;
  const u16* A1p = A1g + base;

  // ---- phase 1: Alpha = Q K^T (contraction over m=512, 8 chunks of 64) ----
  f32x4 accA[4];
#pragma unroll
  for (int yt = 0; yt < 4; ++yt) accA[yt] = {0.0f, 0.0f, 0.0f, 0.0f};

  const int srow = t >> 3, scc = t & 7;
  for (int mc = 0; mc < 8; ++mc) {
#pragma unroll
    for (int it = 0; it < 2; ++it) {
      int row = srow + it * 32;
      int gch = scc ^ ((row ^ (row >> 3)) & 7);  // pre-swizzled global chunk
      u16x8 qv = *(const u16x8*)(Qp + row * 512 + mc * 64 + gch * 8);
      u16x8 kv = *(const u16x8*)(Kp + row * 512 + mc * 64 + gch * 8);
      *(u16x8*)((char*)Qc + row * 128 + scc * 16) = qv;
      *(u16x8*)((char*)Kc + row * 128 + scc * 16) = kv;
    }
    __syncthreads();
    short8 qf[2];
#pragma unroll
    for (int ks = 0; ks < 2; ++ks)
      qf[ks] = *(const short8*)((const char*)Qc + tile_byte(16 * w + lr, ks * 4 + lh));
#pragma unroll
    for (int ks = 0; ks < 2; ++ks)
#pragma unroll
      for (int yt = 0; yt < 4; ++yt) {
        short8 kf = *(const short8*)((const char*)Kc + tile_byte(yt * 16 + lr, ks * 4 + lh));
        accA[yt] = __builtin_amdgcn_mfma_f32_16x16x32_bf16(qf[ks], kf, accA[yt], 0, 0, 0);
      }
    __syncthreads();
  }

  // ---- phase 2: row L2-norm + Alpha_norm -> LDS (wave-local rows) ----
  float rsq[4];
#pragma unroll
  for (int r = 0; r < 4; ++r) {
    float s = 0.0f;
#pragma unroll
    for (int yt = 0; yt < 4; ++yt) s += accA[yt][r] * accA[yt][r];
#pragma unroll
    for (int msk = 1; msk < 16; msk <<= 1) s += __shfl_xor(s, msk);
    rsq[r] = rsqrtf(s);
  }
#pragma unroll
  for (int yt = 0; yt < 4; ++yt)
#pragma unroll
    for (int r = 0; r < 4; ++r) {
      int xr = 16 * w + 4 * lh + r;
      int y = yt * 16 + lr;
      *(u16*)((char*)An + xr * 128 + swzc(xr, y >> 3) * 16 + (y & 7) * 2) =
          f2bf(fabsf(accA[yt][r]) * rsq[r]);
    }

  // ---- phase 3: Y^T = V_t * An^T, fused combine+relu+store+BN partials ----
  float ls = 0.0f, lsq = 0.0f;
  const float* A2p = A2g + ((long)bg * 64 + c) * 2048;  // [x][y]
  const float* A3p = A3g + ((long)bg * 64 + c) * 1024;  // [x][z]
  float* outp = out + (bglob * 64 + c) * 32768;
  const int m4 = t & 15, y4 = t >> 4;
  const int x = 16 * w + lr;

  for (int mc = 0; mc < 8; ++mc) {
    __syncthreads();
    u16x4 vr[4];
#pragma unroll
    for (int r = 0; r < 4; ++r)
      vr[r] = *(const u16x4*)(Vp + (y4 * 4 + r) * 512 + mc * 64 + m4 * 4);
#pragma unroll
    for (int ci = 0; ci < 4; ++ci) {
      int mrow = m4 * 4 + ci;
      u16x4 pk = {vr[0][ci], vr[1][ci], vr[2][ci], vr[3][ci]};
      *(u16x4*)((char*)Vt + tile_byte(mrow, y4 >> 1) + (y4 & 1) * 8) = pk;
    }
    __syncthreads();

    f32x4 accY[4];
#pragma unroll
    for (int mt = 0; mt < 4; ++mt) accY[mt] = {0.0f, 0.0f, 0.0f, 0.0f};
#pragma unroll
    for (int ks = 0; ks < 2; ++ks) {
      short8 anf = *(const short8*)((const char*)An + tile_byte(16 * w + lr, ks * 4 + lh));
#pragma unroll
      for (int mt = 0; mt < 4; ++mt) {
        short8 vf = *(const short8*)((const char*)Vt + tile_byte(mt * 16 + lr, ks * 4 + lh));
        accY[mt] = __builtin_amdgcn_mfma_f32_16x16x32_bf16(vf, anf, accY[mt], 0, 0, 0);
      }
    }
    f32x4 a3v = *(const f32x4*)(A3p + x * 16 + lh * 4);
#pragma unroll
    for (int mt = 0; mt < 4; ++mt) {
      float a2v = A2p[x * 32 + mc * 4 + mt];
      int mbase = mc * 64 + mt * 16 + lh * 4;
      u16x4 a1v = *(const u16x4*)(A1p + x * 512 + mbase);
      f32x4 o;
#pragma unroll
      for (int r = 0; r < 4; ++r) {
        float val = bf2f(a1v[r]) + 0.1f * (a2v + a3v[r] + accY[mt][r]);
        val = fmaxf(val, 0.0f);
        o[r] = val;
        ls += val;
        lsq += val * val;
      }
      *(f32x4*)(outp + x * 512 + mbase) = o;
    }
  }

  // ---- phase 4: deterministic block reduction of BN partials ----
#pragma unroll
  for (int off = 32; off > 0; off >>= 1) {
    ls += __shfl_xor(ls, off);
    lsq += __shfl_xor(lsq, off);
  }
  if (l == 0) {
    red[w] = ls;
    red[4 + w] = lsq;
  }
  __syncthreads();
  if (t == 0) {
    partials[2 * (bglob * 64 + c) + 0] = red[0] + red[1] + red[2] + red[3];
    partials[2 * (bglob * 64 + c) + 1] = red[4] + red[5] + red[6] + red[7];
  }
}

// ---------------- BN stats finalize ----------------
__global__ void k_stats(const float* __restrict__ partials, const float* __restrict__ gamma,
                        const float* __restrict__ beta, float* __restrict__ sb) {
  int c = threadIdx.x;
  if (c >= 64) return;
  float S = 0.0f, SQ = 0.0f;
  for (int b = 0; b < 16; ++b) {
    S += partials[2 * (b * 64 + c) + 0];
    SQ += partials[2 * (b * 64 + c) + 1];
  }
  const float N = 524288.0f;
  float mean = S / N;
  float var = SQ / N - mean * mean;
  float rs = rsqrtf(var + 1e-5f);
  float scale = gamma[c] * rs;
  sb[c] = scale;
  sb[64 + c] = beta[c] - mean * scale;
}

// ---------------- BN affine ----------------
__global__ void k_bn(float* __restrict__ out, const float* __restrict__ sb) {
  long idx = ((long)blockIdx.x * 256 + threadIdx.x) * 4;
  int c = (int)((idx >> 15) & 63);
  float scale = sb[c], bias = sb[64 + c];
  f32x4 v = *(f32x4*)(out + idx);
#pragma unroll
  for (int r = 0; r < 4; ++r) v[r] = v[r] * scale + bias;
  *(f32x4*)(out + idx) = v;
}

extern "C" void kernel_launch(void* const* d_in, const int* in_sizes, int n_in, void* d_out,
                              int out_size, void* d_ws, size_t ws_size, hipStream_t stream) {
  (void)in_sizes; (void)n_in; (void)out_size;
  const float* A = (const float*)d_in[0];
  const float* P1 = (const float*)d_in[1];
  const float* P2 = (const float*)d_in[2];
  const float* P3 = (const float*)d_in[3];
  const float* P4 = (const float*)d_in[4];
  const float* q = (const float*)d_in[5];
  const float* k = (const float*)d_in[6];
  const float* gamma = (const float*)d_in[7];
  const float* beta = (const float*)d_in[8];
  float* out = (float*)d_out;
  char* ws = (char*)d_ws;

  u16* Wbf = (u16*)ws;                     // 48 KiB (6 matrices)
  float* partials = (float*)(ws + 49152);  // 8 KiB
  float* sb = (float*)(ws + 57344);        // 512 B
  const size_t GR = 65536;
  const size_t SZ_M = (size_t)64 * 32768 * 2;    // 4 MiB per batch per matrix (bf16)
  const size_t SZ_A2 = (size_t)64 * 64 * 32 * 4;   // 512 KiB
  const size_t SZ_A3 = (size_t)64 * 64 * 16 * 4;   // 256 KiB
  const size_t perb = 4 * SZ_M + SZ_A2 + SZ_A3;    // ~16.75 MiB
  int G = 1;
  if (ws_size > GR + perb) G = (int)((ws_size - GR) / perb);
  if (G > 16) G = 16;
  if (G < 1) G = 1;

  u16* A1 = (u16*)(ws + GR);
  u16* Qw = (u16*)(ws + GR + (size_t)G * SZ_M);
  u16* Kw = (u16*)(ws + GR + (size_t)G * SZ_M * 2);
  u16* Vw = (u16*)(ws + GR + (size_t)G * SZ_M * 3);
  float* A2 = (float*)(ws + GR + (size_t)G * SZ_M * 4);
  float* A3 = (float*)((char*)A2 + (size_t)G * SZ_A2);

  kw_convert<<<1, 256, 0, stream>>>(P1, q, k, P4, P2, P3, Wbf);
  for (int g0 = 0; g0 < 16; g0 += G) {
    int Gc = (16 - g0) < G ? (16 - g0) : G;
    k_projA<<<dim3(64, Gc), 512, 0, stream>>>(A, Wbf, A1, Qw, Kw, Vw, A2, A3, g0);
    k_attn<<<dim3(64, Gc), 256, 0, stream>>>(Qw, Kw, Vw, A1, A2, A3, out, partials, g0);
  }
  k_stats<<<1, 64, 0, stream>>>(partials, gamma, beta, sb);
  k_bn<<<32768, 256, 0, stream>>>(out, sb);
}

// Round 3
// 271.089 us; speedup vs baseline: 1.3401x; 1.1163x over previous
//
#include <hip/hip_runtime.h>

typedef __attribute__((ext_vector_type(8))) short short8;
typedef __attribute__((ext_vector_type(4))) float f32x4;
typedef __attribute__((ext_vector_type(8))) unsigned short u16x8;
typedef __attribute__((ext_vector_type(4))) unsigned short u16x4;
typedef __attribute__((ext_vector_type(4))) unsigned int u32x4;
typedef unsigned short u16;

#define DEVINL __device__ __forceinline__

DEVINL u16 f2bf(float f) {
  unsigned u = __builtin_bit_cast(unsigned, f);
  unsigned r = (u + 0x7fffu + ((u >> 16) & 1u)) >> 16;  // RNE
  return (u16)r;
}
DEVINL float bf2f(u16 h) {
  unsigned u = ((unsigned)h) << 16;
  return __builtin_bit_cast(float, u);
}
DEVINL unsigned pk2(float a, float b) {
  return (unsigned)f2bf(a) | ((unsigned)f2bf(b) << 16);
}
// LDS tiles: [rows][64 bf16 cols] = 128 B rows = 8 chunks of 16 B.
// XOR swizzle keeps column reads conflict-free; writer & reader share it.
DEVINL int swzc(int row, int chunk) { return chunk ^ ((row ^ (row >> 3)) & 7); }
DEVINL int tile_byte(int row, int chunk) { return row * 128 + swzc(row, chunk) * 16; }

// ---------------- W conversion: P1,q,k,P4,P2,P3 -> bf16 ----------------
__global__ void kw_convert(const float* __restrict__ P1, const float* __restrict__ q,
                           const float* __restrict__ k, const float* __restrict__ P4,
                           const float* __restrict__ P2, const float* __restrict__ P3,
                           u16* __restrict__ Wbf) {
  int t = threadIdx.x;
  const float* srcs[6] = {P1, q, k, P4, P2, P3};
  for (int w = 0; w < 6; ++w)
    for (int e = t; e < 4096; e += 256) Wbf[w * 4096 + e] = f2bf(srcs[w][e]);
}

// ---------------- fused: means + A2/A3 + projections ----------------
// block = (x, bg): reads A[i=0..63][s = x*512 .. +511] once.
__global__ __launch_bounds__(512, 4) void k_projA(
    const float* __restrict__ A, const u16* __restrict__ Wbf, u16* __restrict__ A1,
    u16* __restrict__ Q, u16* __restrict__ Km, u16* __restrict__ V,
    float* __restrict__ A2g, float* __restrict__ A3g, int g0) {
  __shared__ __align__(16) u16 tile[512 * 64];  // [s][i] bf16, swizzled, 64 KiB
  __shared__ __align__(16) u16 meanT[48 * 64];  // rows 0-31: mean3[y][i]; 32-47: mean2[z][i]
  const int t = threadIdx.x;
  const int w = t >> 6, l = t & 63;
  const int lr = l & 15, lh = l >> 4;
  const int x = blockIdx.x, bg = blockIdx.y;
  const long bglob = g0 + bg;

  // ---- stage A -> tile (transpose [i][s] -> [s][i], f32 -> bf16) ----
  {
    const int s4 = t & 31, i4 = t >> 5;  // i = i4*4 + c, s = si*128 + s4*4 + e
    const float* ap = A + (bglob * 64 + i4 * 4) * 32768 + (long)x * 512 + s4 * 4;
#pragma unroll
    for (int si = 0; si < 4; ++si) {
      f32x4 v0 = *(const f32x4*)(ap + si * 128);
      f32x4 v1 = *(const f32x4*)(ap + si * 128 + 32768);
      f32x4 v2 = *(const f32x4*)(ap + si * 128 + 65536);
      f32x4 v3 = *(const f32x4*)(ap + si * 128 + 98304);
#pragma unroll
      for (int e = 0; e < 4; ++e) {
        int s = si * 128 + s4 * 4 + e;
        u16x4 pk = {f2bf(v0[e]), f2bf(v1[e]), f2bf(v2[e]), f2bf(v3[e])};
        *(u16x4*)((char*)tile + tile_byte(s, i4 >> 1) + (i4 & 1) * 8) = pk;
      }
    }
  }
  __syncthreads();

  // ---- mean3[y][i] = (1/16) sum_z tile[y*16+z][i]  (t -> ic, zh, y) ----
  {
    const int ic = t & 7, zh = (t >> 3) & 1, y = t >> 4;  // y in 0..31
    float acc[8] = {0, 0, 0, 0, 0, 0, 0, 0};
#pragma unroll
    for (int zz = 0; zz < 8; ++zz) {
      int row = y * 16 + zh * 8 + zz;
      u16x8 v = *(const u16x8*)((const char*)tile + tile_byte(row, ic));
#pragma unroll
      for (int e = 0; e < 8; ++e) acc[e] += bf2f(v[e]);
    }
#pragma unroll
    for (int e = 0; e < 8; ++e) acc[e] += __shfl_xor(acc[e], 8);
    if (zh == 0) {
      u16x8 pk;
#pragma unroll
      for (int e = 0; e < 8; ++e) pk[e] = f2bf(acc[e] * (1.0f / 16.0f));
      *(u16x8*)((char*)meanT + tile_byte(y, ic)) = pk;
    }
  }
  // ---- mean2[z][i] = (1/32) sum_y tile[y*16+z][i]  (t -> ic, yg, z) ----
  {
    const int ic = t & 7, yg = (t >> 3) & 3, z = t >> 5;  // z in 0..15
    float acc[8] = {0, 0, 0, 0, 0, 0, 0, 0};
#pragma unroll
    for (int yy = 0; yy < 8; ++yy) {
      int row = (yg * 8 + yy) * 16 + z;
      u16x8 v = *(const u16x8*)((const char*)tile + tile_byte(row, ic));
#pragma unroll
      for (int e = 0; e < 8; ++e) acc[e] += bf2f(v[e]);
    }
#pragma unroll
    for (int e = 0; e < 8; ++e) {
      acc[e] += __shfl_xor(acc[e], 8);
      acc[e] += __shfl_xor(acc[e], 16);
    }
    if (yg == 0) {
      u16x8 pk;
#pragma unroll
      for (int e = 0; e < 8; ++e) pk[e] = f2bf(acc[e] * (1.0f / 32.0f));
      *(u16x8*)((char*)meanT + tile_byte(32 + z, ic)) = pk;
    }
  }
  __syncthreads();

  // ---- A2/A3 via MFMA on waves 0-2: D[o][col] = W{P2,P3} . meanT ----
  if (w < 3) {
    const int ct = w;  // 0,1: A2 col-tiles (y); 2: A3 (z), meanT rows 32..47
    const u16* wb2 = Wbf + (w == 2 ? 5 : 4) * 4096;
    const int colrow = (w == 2) ? 32 + lr : ct * 16 + lr;
    f32x4 acc2[4];
#pragma unroll
    for (int ot = 0; ot < 4; ++ot) acc2[ot] = {0.0f, 0.0f, 0.0f, 0.0f};
#pragma unroll
    for (int ks = 0; ks < 2; ++ks) {
      short8 mf = *(const short8*)((const char*)meanT + tile_byte(colrow, ks * 4 + lh));
#pragma unroll
      for (int ot = 0; ot < 4; ++ot) {
        short8 w2f = *(const short8*)(wb2 + (ot * 16 + lr) * 64 + ks * 32 + lh * 8);
        acc2[ot] = __builtin_amdgcn_mfma_f32_16x16x32_bf16(w2f, mf, acc2[ot], 0, 0, 0);
      }
    }
    // D[o][col]: lane col = lr, rows o = ot*16 + lh*4 + r
#pragma unroll
    for (int ot = 0; ot < 4; ++ot)
#pragma unroll
      for (int r = 0; r < 4; ++r) {
        int o = ot * 16 + lh * 4 + r;
        if (w < 2)
          A2g[(((long)bg * 64 + o) * 64 + x) * 32 + ct * 16 + lr] = acc2[ot][r];
        else
          A3g[(((long)bg * 64 + o) * 64 + x) * 16 + lr] = acc2[ot][r];
      }
  }

  // ---- main: A1,Q,K,V = {P1,q,k,P4} @ A (wave = matrix x s-half) ----
  // st processed in pairs; shfl_xor(16) pairs lh<->lh^1 (same o, s +/-4) so each
  // lane stores a 16 B contiguous s-run -> per store instr: 16 o-rows x 64 B.
  const int m = w & 3, sh = w >> 2;
  const u16* wb = Wbf + m * 4096;
  short8 wf[4][2];
#pragma unroll
  for (int ot = 0; ot < 4; ++ot)
#pragma unroll
    for (int ks = 0; ks < 2; ++ks)
      wf[ot][ks] = *(const short8*)(wb + (ot * 16 + lr) * 64 + ks * 32 + lh * 8);
  u16* outp = (m == 0) ? A1 : (m == 1) ? Q : (m == 2) ? Km : V;
  outp += (long)bg * 64 * 32768;
  const int odd = lh & 1;
  const int p8 = (lh >> 1) * 8;

  for (int stp = 0; stp < 8; ++stp) {
    const int srowE = sh * 256 + stp * 32 + lr;
    const int srowO = srowE + 16;
    short8 aE0 = *(const short8*)((const char*)tile + tile_byte(srowE, lh));
    short8 aE1 = *(const short8*)((const char*)tile + tile_byte(srowE, 4 + lh));
    short8 aO0 = *(const short8*)((const char*)tile + tile_byte(srowO, lh));
    short8 aO1 = *(const short8*)((const char*)tile + tile_byte(srowO, 4 + lh));
    const int sbase = x * 512 + sh * 256 + stp * 32 + odd * 16 + p8;
#pragma unroll
    for (int ot = 0; ot < 4; ++ot) {
      f32x4 accE = {0.0f, 0.0f, 0.0f, 0.0f}, accO = {0.0f, 0.0f, 0.0f, 0.0f};
      accE = __builtin_amdgcn_mfma_f32_16x16x32_bf16(aE0, wf[ot][0], accE, 0, 0, 0);
      accE = __builtin_amdgcn_mfma_f32_16x16x32_bf16(aE1, wf[ot][1], accE, 0, 0, 0);
      accO = __builtin_amdgcn_mfma_f32_16x16x32_bf16(aO0, wf[ot][0], accO, 0, 0, 0);
      accO = __builtin_amdgcn_mfma_f32_16x16x32_bf16(aO1, wf[ot][1], accO, 0, 0, 0);
      unsigned pE0 = pk2(accE[0], accE[1]), pE1 = pk2(accE[2], accE[3]);
      unsigned pO0 = pk2(accO[0], accO[1]), pO1 = pk2(accO[2], accO[3]);
      unsigned rE0 = __shfl_xor((int)pE0, 16), rE1 = __shfl_xor((int)pE1, 16);
      unsigned rO0 = __shfl_xor((int)pO0, 16), rO1 = __shfl_xor((int)pO1, 16);
      u32x4 sv;
      if (odd) sv = (u32x4){rO0, rO1, pO0, pO1};
      else     sv = (u32x4){pE0, pE1, rE0, rE1};
      *(u32x4*)(outp + (long)(ot * 16 + lr) * 32768 + sbase) = sv;
    }
  }
}

// ---------------- attention + combine + relu + BN partials ----------------
__global__ __launch_bounds__(256) void k_attn(const u16* __restrict__ Qg,
                                              const u16* __restrict__ Kg,
                                              const u16* __restrict__ Vg,
                                              const u16* __restrict__ A1g,
                                              const float* __restrict__ A2g,
                                              const float* __restrict__ A3g,
                                              float* __restrict__ out,
                                              float* __restrict__ partials, int g0) {
  __shared__ __align__(16) u16 Qc[4096], Kc[4096], Vt[4096], An[4096];
  __shared__ float red[8];
  const int t = threadIdx.x, w = t >> 6, l = t & 63;
  const int lr = l & 15, lh = l >> 4;
  const int c = blockIdx.x, bg = blockIdx.y;
  const long bglob = g0 + bg;
  const long base = ((long)bg * 64 + c) * 32768;
  const u16* Qp = Qg + base;
  const u16* Kp = Kg + base;
  const u16* Vp = Vg + base;
  const u16* A1p = A1g + base;

  // ---- phase 1: Alpha = Q K^T (contraction over m=512, 8 chunks of 64) ----
  f32x4 accA[4];
#pragma unroll
  for (int yt = 0; yt < 4; ++yt) accA[yt] = {0.0f, 0.0f, 0.0f, 0.0f};

  const int srow = t >> 3, scc = t & 7;
  for (int mc = 0; mc < 8; ++mc) {
#pragma unroll
    for (int it = 0; it < 2; ++it) {
      int row = srow + it * 32;
      int gch = scc ^ ((row ^ (row >> 3)) & 7);  // pre-swizzled global chunk
      u16x8 qv = *(const u16x8*)(Qp + row * 512 + mc * 64 + gch * 8);
      u16x8 kv = *(const u16x8*)(Kp + row * 512 + mc * 64 + gch * 8);
      *(u16x8*)((char*)Qc + row * 128 + scc * 16) = qv;
      *(u16x8*)((char*)Kc + row * 128 + scc * 16) = kv;
    }
    __syncthreads();
    short8 qf[2];
#pragma unroll
    for (int ks = 0; ks < 2; ++ks)
      qf[ks] = *(const short8*)((const char*)Qc + tile_byte(16 * w + lr, ks * 4 + lh));
#pragma unroll
    for (int ks = 0; ks < 2; ++ks)
#pragma unroll
      for (int yt = 0; yt < 4; ++yt) {
        short8 kf = *(const short8*)((const char*)Kc + tile_byte(yt * 16 + lr, ks * 4 + lh));
        accA[yt] = __builtin_amdgcn_mfma_f32_16x16x32_bf16(qf[ks], kf, accA[yt], 0, 0, 0);
      }
    __syncthreads();
  }

  // ---- phase 2: row L2-norm + Alpha_norm -> LDS (wave-local rows) ----
  float rsq[4];
#pragma unroll
  for (int r = 0; r < 4; ++r) {
    float s = 0.0f;
#pragma unroll
    for (int yt = 0; yt < 4; ++yt) s += accA[yt][r] * accA[yt][r];
#pragma unroll
    for (int msk = 1; msk < 16; msk <<= 1) s += __shfl_xor(s, msk);
    rsq[r] = rsqrtf(s);
  }
#pragma unroll
  for (int yt = 0; yt < 4; ++yt)
#pragma unroll
    for (int r = 0; r < 4; ++r) {
      int xr = 16 * w + 4 * lh + r;
      int y = yt * 16 + lr;
      *(u16*)((char*)An + xr * 128 + swzc(xr, y >> 3) * 16 + (y & 7) * 2) =
          f2bf(fabsf(accA[yt][r]) * rsq[r]);
    }

  // ---- phase 3: Y^T = V_t * An^T, fused combine+relu+store+BN partials ----
  float ls = 0.0f, lsq = 0.0f;
  const float* A2p = A2g + ((long)bg * 64 + c) * 2048;  // [x][y]
  const float* A3p = A3g + ((long)bg * 64 + c) * 1024;  // [x][z]
  float* outp = out + (bglob * 64 + c) * 32768;
  const int m4 = t & 15, y4 = t >> 4;
  const int x = 16 * w + lr;

  for (int mc = 0; mc < 8; ++mc) {
    __syncthreads();
    u16x4 vr[4];
#pragma unroll
    for (int r = 0; r < 4; ++r)
      vr[r] = *(const u16x4*)(Vp + (y4 * 4 + r) * 512 + mc * 64 + m4 * 4);
#pragma unroll
    for (int ci = 0; ci < 4; ++ci) {
      int mrow = m4 * 4 + ci;
      u16x4 pk = {vr[0][ci], vr[1][ci], vr[2][ci], vr[3][ci]};
      *(u16x4*)((char*)Vt + tile_byte(mrow, y4 >> 1) + (y4 & 1) * 8) = pk;
    }
    __syncthreads();

    f32x4 accY[4];
#pragma unroll
    for (int mt = 0; mt < 4; ++mt) accY[mt] = {0.0f, 0.0f, 0.0f, 0.0f};
#pragma unroll
    for (int ks = 0; ks < 2; ++ks) {
      short8 anf = *(const short8*)((const char*)An + tile_byte(16 * w + lr, ks * 4 + lh));
#pragma unroll
      for (int mt = 0; mt < 4; ++mt) {
        short8 vf = *(const short8*)((const char*)Vt + tile_byte(mt * 16 + lr, ks * 4 + lh));
        accY[mt] = __builtin_amdgcn_mfma_f32_16x16x32_bf16(vf, anf, accY[mt], 0, 0, 0);
      }
    }
    f32x4 a3v = *(const f32x4*)(A3p + x * 16 + lh * 4);
#pragma unroll
    for (int mt = 0; mt < 4; ++mt) {
      float a2v = A2p[x * 32 + mc * 4 + mt];
      int mbase = mc * 64 + mt * 16 + lh * 4;
      u16x4 a1v = *(const u16x4*)(A1p + x * 512 + mbase);
      f32x4 o;
#pragma unroll
      for (int r = 0; r < 4; ++r) {
        float val = bf2f(a1v[r]) + 0.1f * (a2v + a3v[r] + accY[mt][r]);
        val = fmaxf(val, 0.0f);
        o[r] = val;
        ls += val;
        lsq += val * val;
      }
      *(f32x4*)(outp + x * 512 + mbase) = o;
    }
  }

  // ---- phase 4: deterministic block reduction of BN partials ----
#pragma unroll
  for (int off = 32; off > 0; off >>= 1) {
    ls += __shfl_xor(ls, off);
    lsq += __shfl_xor(lsq, off);
  }
  if (l == 0) {
    red[w] = ls;
    red[4 + w] = lsq;
  }
  __syncthreads();
  if (t == 0) {
    partials[2 * (bglob * 64 + c) + 0] = red[0] + red[1] + red[2] + red[3];
    partials[2 * (bglob * 64 + c) + 1] = red[4] + red[5] + red[6] + red[7];
  }
}

// ---------------- BN stats finalize ----------------
__global__ void k_stats(const float* __restrict__ partials, const float* __restrict__ gamma,
                        const float* __restrict__ beta, float* __restrict__ sb) {
  int c = threadIdx.x;
  if (c >= 64) return;
  float S = 0.0f, SQ = 0.0f;
  for (int b = 0; b < 16; ++b) {
    S += partials[2 * (b * 64 + c) + 0];
    SQ += partials[2 * (b * 64 + c) + 1];
  }
  const float N = 524288.0f;
  float mean = S / N;
  float var = SQ / N - mean * mean;
  float rs = rsqrtf(var + 1e-5f);
  float scale = gamma[c] * rs;
  sb[c] = scale;
  sb[64 + c] = beta[c] - mean * scale;
}

// ---------------- BN affine ----------------
__global__ void k_bn(float* __restrict__ out, const float* __restrict__ sb) {
  long idx = ((long)blockIdx.x * 256 + threadIdx.x) * 4;
  int c = (int)((idx >> 15) & 63);
  float scale = sb[c], bias = sb[64 + c];
  f32x4 v = *(f32x4*)(out + idx);
#pragma unroll
  for (int r = 0; r < 4; ++r) v[r] = v[r] * scale + bias;
  *(f32x4*)(out + idx) = v;
}

extern "C" void kernel_launch(void* const* d_in, const int* in_sizes, int n_in, void* d_out,
                              int out_size, void* d_ws, size_t ws_size, hipStream_t stream) {
  (void)in_sizes; (void)n_in; (void)out_size;
  const float* A = (const float*)d_in[0];
  const float* P1 = (const float*)d_in[1];
  const float* P2 = (const float*)d_in[2];
  const float* P3 = (const float*)d_in[3];
  const float* P4 = (const float*)d_in[4];
  const float* q = (const float*)d_in[5];
  const float* k = (const float*)d_in[6];
  const float* gamma = (const float*)d_in[7];
  const float* beta = (const float*)d_in[8];
  float* out = (float*)d_out;
  char* ws = (char*)d_ws;

  u16* Wbf = (u16*)ws;                     // 48 KiB (6 matrices)
  float* partials = (float*)(ws + 49152);  // 8 KiB
  float* sb = (float*)(ws + 57344);        // 512 B
  const size_t GR = 65536;
  const size_t SZ_M = (size_t)64 * 32768 * 2;    // 4 MiB per batch per matrix (bf16)
  const size_t SZ_A2 = (size_t)64 * 64 * 32 * 4;   // 512 KiB
  const size_t SZ_A3 = (size_t)64 * 64 * 16 * 4;   // 256 KiB
  const size_t perb = 4 * SZ_M + SZ_A2 + SZ_A3;    // ~16.75 MiB
  int G = 1;
  if (ws_size > GR + perb) G = (int)((ws_size - GR) / perb);
  if (G > 16) G = 16;
  if (G < 1) G = 1;

  u16* A1 = (u16*)(ws + GR);
  u16* Qw = (u16*)(ws + GR + (size_t)G * SZ_M);
  u16* Kw = (u16*)(ws + GR + (size_t)G * SZ_M * 2);
  u16* Vw = (u16*)(ws + GR + (size_t)G * SZ_M * 3);
  float* A2 = (float*)(ws + GR + (size_t)G * SZ_M * 4);
  float* A3 = (float*)((char*)A2 + (size_t)G * SZ_A2);

  kw_convert<<<1, 256, 0, stream>>>(P1, q, k, P4, P2, P3, Wbf);
  for (int g0 = 0; g0 < 16; g0 += G) {
    int Gc = (16 - g0) < G ? (16 - g0) : G;
    k_projA<<<dim3(64, Gc), 512, 0, stream>>>(A, Wbf, A1, Qw, Kw, Vw, A2, A3, g0);
    k_attn<<<dim3(64, Gc), 256, 0, stream>>>(Qw, Kw, Vw, A1, A2, A3, out, partials, g0);
  }
  k_stats<<<1, 64, 0, stream>>>(partials, gamma, beta, sb);
  k_bn<<<32768, 256, 0, stream>>>(out, sb);
}